// Round 1
// baseline (232.742 us; speedup 1.0000x reference)
//
#include <hip/hip_runtime.h>

// ScRRAMBLe capsule layer, fused:
//   xr[i,r,m] = sum_{ij} Ci[ij, i, r] * x[ij, m]        (ij = 2048, r = 4, m = 64)
//   y[i,j,l]  = sum_{k,m} Wi[i,j,k,l,m] * xr[i,k,m]     (i = 512, j = 4, l = 64)
//
// One block per capsule i (512 blocks, 256 threads = 4 waves).
// Phase 1: routing einsum, ij split 16 ways, LDS reduce -> xr in LDS.
// Phase 2: wave = j; lane reads float4 of Wi row (perfectly coalesced,
//          read-once, 1 KiB per wave instruction), 16-lane shfl reduce.

__global__ __launch_bounds__(256) void caps_fused(
    const float* __restrict__ x,
    const float* __restrict__ Ci,
    const float* __restrict__ Wi,
    float* __restrict__ y)
{
    const int i    = blockIdx.x;    // output capsule
    const int t    = threadIdx.x;   // 0..255
    const int lane = t & 63;

    __shared__ float part[16 * 256];  // 16 KiB phase-1 partials
    __shared__ float xr[256];         // xr[i, k, m] = xr[k*64 + m]

    // ---------------- Phase 1: xr[r][m] = sum_ij Ci[ij,i,r] * x[ij,m] ----
    // thread t: ij-group g = t/16 (128 ij each), m-quad mq4 = t%16 (m = 4*mq4..+3)
    const int g   = t >> 4;
    const int mq4 = t & 15;

    const float4* __restrict__ Ci4 = reinterpret_cast<const float4*>(Ci);
    const float4* __restrict__ x4p = reinterpret_cast<const float4*>(x);

    float4 acc0 = make_float4(0.f, 0.f, 0.f, 0.f);  // r = 0, m quad
    float4 acc1 = make_float4(0.f, 0.f, 0.f, 0.f);
    float4 acc2 = make_float4(0.f, 0.f, 0.f, 0.f);
    float4 acc3 = make_float4(0.f, 0.f, 0.f, 0.f);

    const int ijbase = g << 7;  // g*128
    #pragma unroll 4
    for (int it = 0; it < 128; ++it) {
        const int ij = ijbase + it;
        // Ci[ij*2048 + i*4 + (0..3)] as one float4 (shared by 16 lanes)
        const float4 c4 = Ci4[ij * 512 + i];
        // x[ij*64 + 4*mq4 + (0..3)]
        const float4 xv = x4p[(ij << 4) + mq4];
        acc0.x += c4.x * xv.x; acc0.y += c4.x * xv.y; acc0.z += c4.x * xv.z; acc0.w += c4.x * xv.w;
        acc1.x += c4.y * xv.x; acc1.y += c4.y * xv.y; acc1.z += c4.y * xv.z; acc1.w += c4.y * xv.w;
        acc2.x += c4.z * xv.x; acc2.y += c4.z * xv.y; acc2.z += c4.z * xv.z; acc2.w += c4.z * xv.w;
        acc3.x += c4.w * xv.x; acc3.y += c4.w * xv.y; acc3.z += c4.w * xv.z; acc3.w += c4.w * xv.w;
    }

    // part[g*256 + r*64 + 4*mq4 + q]
    {
        float4* p4 = reinterpret_cast<float4*>(part);
        p4[(g << 6) + (0 << 4) + mq4] = acc0;
        p4[(g << 6) + (1 << 4) + mq4] = acc1;
        p4[(g << 6) + (2 << 4) + mq4] = acc2;
        p4[(g << 6) + (3 << 4) + mq4] = acc3;
    }
    __syncthreads();

    // reduce 16 partials: thread t owns xr element t = r*64 + m
    {
        float s = 0.f;
        #pragma unroll
        for (int gg = 0; gg < 16; ++gg) s += part[(gg << 8) + t];
        xr[t] = s;
    }
    __syncthreads();

    // ---------------- Phase 2: y[i,j,l] = sum_{k,m} Wi[i,j,k,l,m]*xr[k,m] --
    const int j   = t >> 6;        // wave index = output rf slot
    const int lq  = lane >> 4;     // l sub-index 0..3
    const int m16 = lane & 15;     // m quad index within row

    const float4* __restrict__ W4 = reinterpret_cast<const float4*>(Wi);
    const int wbase = (i * 4 + j) * 4096;   // float4 units; max < 2^23, int ok

    // xr fragments for this lane's m quad, per k
    float4 xr0 = reinterpret_cast<const float4*>(xr)[0 * 16 + m16];
    float4 xr1 = reinterpret_cast<const float4*>(xr)[1 * 16 + m16];
    float4 xr2 = reinterpret_cast<const float4*>(xr)[2 * 16 + m16];
    float4 xr3 = reinterpret_cast<const float4*>(xr)[3 * 16 + m16];

    #pragma unroll 4
    for (int l0 = 0; l0 < 64; l0 += 4) {
        const int l = l0 + lq;
        float p = 0.f;
        {
            const float4 w = W4[wbase + 0 * 1024 + l * 16 + m16];
            p += w.x * xr0.x + w.y * xr0.y + w.z * xr0.z + w.w * xr0.w;
        }
        {
            const float4 w = W4[wbase + 1 * 1024 + l * 16 + m16];
            p += w.x * xr1.x + w.y * xr1.y + w.z * xr1.z + w.w * xr1.w;
        }
        {
            const float4 w = W4[wbase + 2 * 1024 + l * 16 + m16];
            p += w.x * xr2.x + w.y * xr2.y + w.z * xr2.z + w.w * xr2.w;
        }
        {
            const float4 w = W4[wbase + 3 * 1024 + l * 16 + m16];
            p += w.x * xr3.x + w.y * xr3.y + w.z * xr3.z + w.w * xr3.w;
        }
        // reduce across the 16 lanes sharing (j, l)
        p += __shfl_xor(p, 1);
        p += __shfl_xor(p, 2);
        p += __shfl_xor(p, 4);
        p += __shfl_xor(p, 8);
        if (m16 == 0) y[(i * 4 + j) * 64 + l] = p;
    }
}

extern "C" void kernel_launch(void* const* d_in, const int* in_sizes, int n_in,
                              void* d_out, int out_size, void* d_ws, size_t ws_size,
                              hipStream_t stream) {
    const float* x  = (const float*)d_in[0];   // 131072
    const float* Ci = (const float*)d_in[1];   // 512*4*512*4
    const float* Wi = (const float*)d_in[2];   // 512*4*4*64*64
    float* y = (float*)d_out;                  // 512*4*64
    caps_fused<<<512, 256, 0, stream>>>(x, Ci, Wi, y);
}

// Round 2
// 231.442 us; speedup vs baseline: 1.0056x; 1.0056x over previous
//
#include <hip/hip_runtime.h>

// ScRRAMBLe capsule layer, two-kernel split for occupancy:
//   A) xr[i,k,m] = sum_ij Ci[ij, i*4+k] * x[ij, m]   -> partials in d_ws
//   B) y[i,j,l]  = sum_{k,m} Wi[i,j,k,l,m] * xr[i,k,m]
//
// R0 post-mortem: fused kernel had 512 blocks = 2 blocks/CU = 19.6% occupancy
// -> HBM stuck at 1.57 TB/s (19.7%) despite perfect 133 MB fetch. Split gives
// 2048 blocks per kernel = 32 waves/CU.

// ---------------- Kernel A: routing einsum, partial over ij chunks ---------
// grid (512, CH); block 256. Chunk c covers ij in [c*ijpc, (c+1)*ijpc).
// Writes xr_part[(c*512 + i)*256 + t].
__global__ __launch_bounds__(256) void route_kernel(
    const float* __restrict__ x,
    const float* __restrict__ Ci,
    float* __restrict__ xr_part,
    int ijpc)
{
    const int i = blockIdx.x;
    const int c = blockIdx.y;
    const int t = threadIdx.x;
    const int g   = t >> 4;   // ij sub-group 0..15
    const int mq4 = t & 15;   // m quad

    __shared__ float part[16 * 256];

    const float4* __restrict__ Ci4 = reinterpret_cast<const float4*>(Ci);
    const float4* __restrict__ x4p = reinterpret_cast<const float4*>(x);

    float4 acc0 = make_float4(0.f,0.f,0.f,0.f);
    float4 acc1 = make_float4(0.f,0.f,0.f,0.f);
    float4 acc2 = make_float4(0.f,0.f,0.f,0.f);
    float4 acc3 = make_float4(0.f,0.f,0.f,0.f);

    const int iters  = ijpc >> 4;           // per g-group
    const int ijbase = c * ijpc + g * iters;
    #pragma unroll 4
    for (int it = 0; it < iters; ++it) {
        const int ij = ijbase + it;
        const float4 c4 = Ci4[ij * 512 + i];     // Ci[ij, i, 0:4]
        const float4 xv = x4p[(ij << 4) + mq4];  // x[ij, 4*mq4 .. +3]
        acc0.x += c4.x * xv.x; acc0.y += c4.x * xv.y; acc0.z += c4.x * xv.z; acc0.w += c4.x * xv.w;
        acc1.x += c4.y * xv.x; acc1.y += c4.y * xv.y; acc1.z += c4.y * xv.z; acc1.w += c4.y * xv.w;
        acc2.x += c4.z * xv.x; acc2.y += c4.z * xv.y; acc2.z += c4.z * xv.z; acc2.w += c4.z * xv.w;
        acc3.x += c4.w * xv.x; acc3.y += c4.w * xv.y; acc3.z += c4.w * xv.z; acc3.w += c4.w * xv.w;
    }

    {
        float4* p4 = reinterpret_cast<float4*>(part);
        p4[(g << 6) + (0 << 4) + mq4] = acc0;
        p4[(g << 6) + (1 << 4) + mq4] = acc1;
        p4[(g << 6) + (2 << 4) + mq4] = acc2;
        p4[(g << 6) + (3 << 4) + mq4] = acc3;
    }
    __syncthreads();

    float s = 0.f;
    #pragma unroll
    for (int gg = 0; gg < 16; ++gg) s += part[(gg << 8) + t];
    xr_part[(c * 512 + i) * 256 + t] = s;
}

// ---------------- Kernel B: per-capsule transform --------------------------
// grid 2048 = (i,j); block 256 = 4 waves; wave w owns l in [w*16, w*16+16).
__global__ __launch_bounds__(256) void transform_kernel(
    const float* __restrict__ Wi,
    const float* __restrict__ xr_part,
    float* __restrict__ y,
    int nchunks)
{
    const int b    = blockIdx.x;      // i*4 + j
    const int i    = b >> 2;
    const int t    = threadIdx.x;
    const int lane = t & 63;
    const int w    = t >> 6;          // wave -> l block
    const int lq   = lane >> 4;       // l sub 0..3
    const int m16  = lane & 15;       // m quad

    // Gather xr[i, k, m16*4 .. +3] for k=0..3, summed over chunks.
    const float4* __restrict__ xp4 = reinterpret_cast<const float4*>(xr_part);
    float4 xr0 = make_float4(0.f,0.f,0.f,0.f);
    float4 xr1 = make_float4(0.f,0.f,0.f,0.f);
    float4 xr2 = make_float4(0.f,0.f,0.f,0.f);
    float4 xr3 = make_float4(0.f,0.f,0.f,0.f);
    for (int c = 0; c < nchunks; ++c) {
        const int base = (c * 512 + i) * 64;  // float4 units
        float4 v;
        v = xp4[base + 0*16 + m16]; xr0.x += v.x; xr0.y += v.y; xr0.z += v.z; xr0.w += v.w;
        v = xp4[base + 1*16 + m16]; xr1.x += v.x; xr1.y += v.y; xr1.z += v.z; xr1.w += v.w;
        v = xp4[base + 2*16 + m16]; xr2.x += v.x; xr2.y += v.y; xr2.z += v.z; xr2.w += v.w;
        v = xp4[base + 3*16 + m16]; xr3.x += v.x; xr3.y += v.y; xr3.z += v.z; xr3.w += v.w;
    }

    const float4* __restrict__ W4 = reinterpret_cast<const float4*>(Wi);
    const int wbase = b * 4096;   // float4 units (max 2048*4096 < 2^23)
    const int lw    = w << 4;

    #pragma unroll
    for (int c2 = 0; c2 < 4; ++c2) {
        const int l = lw + (c2 << 2) + lq;
        float p = 0.f;
        {
            const float4 wv = W4[wbase + 0*1024 + l*16 + m16];
            p += wv.x*xr0.x + wv.y*xr0.y + wv.z*xr0.z + wv.w*xr0.w;
        }
        {
            const float4 wv = W4[wbase + 1*1024 + l*16 + m16];
            p += wv.x*xr1.x + wv.y*xr1.y + wv.z*xr1.z + wv.w*xr1.w;
        }
        {
            const float4 wv = W4[wbase + 2*1024 + l*16 + m16];
            p += wv.x*xr2.x + wv.y*xr2.y + wv.z*xr2.z + wv.w*xr2.w;
        }
        {
            const float4 wv = W4[wbase + 3*1024 + l*16 + m16];
            p += wv.x*xr3.x + wv.y*xr3.y + wv.z*xr3.z + wv.w*xr3.w;
        }
        p += __shfl_xor(p, 1);
        p += __shfl_xor(p, 2);
        p += __shfl_xor(p, 4);
        p += __shfl_xor(p, 8);
        if (m16 == 0) y[b * 64 + l] = p;
    }
}

extern "C" void kernel_launch(void* const* d_in, const int* in_sizes, int n_in,
                              void* d_out, int out_size, void* d_ws, size_t ws_size,
                              hipStream_t stream) {
    const float* x  = (const float*)d_in[0];   // 131072
    const float* Ci = (const float*)d_in[1];   // 512*4*512*4
    const float* Wi = (const float*)d_in[2];   // 512*4*4*64*64
    float* y  = (float*)d_out;                 // 512*4*64
    float* xr = (float*)d_ws;

    // chunked ij-split if workspace allows (4 * 512 * 256 floats = 2 MiB)
    int nchunks = (ws_size >= (size_t)4 * 512 * 256 * sizeof(float)) ? 4 : 1;
    int ijpc    = 2048 / nchunks;

    route_kernel<<<dim3(512, nchunks), 256, 0, stream>>>(x, Ci, xr, ijpc);
    transform_kernel<<<2048, 256, 0, stream>>>(Wi, xr, y, nchunks);
}

// Round 3
// 223.431 us; speedup vs baseline: 1.0417x; 1.0359x over previous
//
#include <hip/hip_runtime.h>

// ScRRAMBLe capsule layer, two-kernel split, MLP-optimized.
//   A) xr[i,k,m] = sum_ij Ci[ij, i, k] * x[ij, m]    -> chunk partials in d_ws
//   B) y[i,j,l]  = sum_{k,m} Wi[i,j,k,l,m] * xr[i,k,m]
//
// R2 post-mortem: 4x occupancy gave ~0 speedup -> not wave-limited. VGPR=36
// shows the compiler kept only 4 Wi loads in flight per wave (vmcnt(0) per
// iter, full HBM latency each). R3: hoist all 16 loads (nontemporal) before
// any FMA; route reworked to i-quad blocks for full Ci cacheline use in L1.

typedef float f4 __attribute__((ext_vector_type(4)));

#define NCH 8   // ij chunks for routing kernel (xr partials: NCH*512*256 floats)

// ---------------- Kernel A: routing einsum ---------------------------------
// grid (128 i-quads, NCH); block 256.
// thread t: il = t>>6 (i within quad), g = (t>>4)&3 (ij subgroup), mq4 = t&15.
__global__ __launch_bounds__(256) void route_kernel(
    const float* __restrict__ x,
    const float* __restrict__ Ci,
    float* __restrict__ xr_part)
{
    const int iq  = blockIdx.x;
    const int c   = blockIdx.y;
    const int t   = threadIdx.x;
    const int il  = t >> 6;
    const int g   = (t >> 4) & 3;
    const int mq4 = t & 15;
    const int i   = (iq << 2) + il;

    const f4* __restrict__ Ci4 = (const f4*)Ci;
    const f4* __restrict__ x4  = (const f4*)x;

    __shared__ f4 part[1024];   // [g][il][r][mq4] = ((g*4+il)*4+r)*16+mq4

    f4 a0 = {0.f,0.f,0.f,0.f};
    f4 a1 = {0.f,0.f,0.f,0.f};
    f4 a2 = {0.f,0.f,0.f,0.f};
    f4 a3 = {0.f,0.f,0.f,0.f};

    const int ijpc = 2048 / NCH;      // 256
    const int sub  = ijpc >> 2;       // 64 per g-subgroup
    const int base = c * ijpc + g * sub;
    #pragma unroll 4
    for (int it = 0; it < sub; ++it) {
        const int ij = base + it;
        const f4 c4 = Ci4[ij * 512 + i];      // Ci[ij, i, 0:4] (16B of a 64B
                                              // line; other 3 i of the quad
                                              // consumed by sibling waves -> L1)
        const f4 xv = x4[(ij << 4) + mq4];    // x[ij, 4*mq4 .. +3]
        a0 += c4.x * xv;
        a1 += c4.y * xv;
        a2 += c4.z * xv;
        a3 += c4.w * xv;
    }

    const int pb = ((g << 2) + il) << 2;      // (g*4+il)*4
    part[(pb + 0) * 16 + mq4] = a0;
    part[(pb + 1) * 16 + mq4] = a1;
    part[(pb + 2) * 16 + mq4] = a2;
    part[(pb + 3) * 16 + mq4] = a3;
    __syncthreads();

    // reduce over g: thread t owns (il2 = t>>6, r = (t>>4)&3, mm = t&15)
    const int il2 = t >> 6;
    const int r   = (t >> 4) & 3;
    const int mm  = t & 15;
    f4 s = {0.f,0.f,0.f,0.f};
    #pragma unroll
    for (int gg = 0; gg < 4; ++gg)
        s += part[(((gg << 2) + il2) * 4 + r) * 16 + mm];

    f4* __restrict__ xp4 = (f4*)xr_part;
    xp4[(c * 512 + (iq << 2) + il2) * 64 + r * 16 + mm] = s;
}

// ---------------- Kernel B: per-capsule transform --------------------------
// grid 2048 = (i*4+j); block 256; wave w owns l in [w*16, w*16+16).
// All 16 Wi loads hoisted + nontemporal: 16 independent loads in flight/lane.
__global__ __launch_bounds__(256, 4) void transform_kernel(
    const float* __restrict__ Wi,
    const float* __restrict__ xr_part,
    float* __restrict__ y)
{
    const int b    = blockIdx.x;
    const int i    = b >> 2;
    const int t    = threadIdx.x;
    const int lane = t & 63;
    const int w    = t >> 6;
    const int lq   = lane >> 4;
    const int m16  = lane & 15;

    // Issue Wi loads FIRST (independent, nontemporal), then gather xr.
    const f4* __restrict__ W4 = (const f4*)Wi;
    const int wbase = b * 4096;
    const int lw    = w << 4;

    f4 wv[16];
    #pragma unroll
    for (int c2 = 0; c2 < 4; ++c2) {
        const int l = lw + (c2 << 2) + lq;
        #pragma unroll
        for (int k = 0; k < 4; ++k)
            wv[(c2 << 2) + k] =
                __builtin_nontemporal_load(&W4[wbase + (k << 10) + l * 16 + m16]);
    }

    // xr[i,k,m16*4..+3] summed over NCH chunk partials (L2/L3-resident).
    const f4* __restrict__ xp4 = (const f4*)xr_part;
    f4 xr0 = {0.f,0.f,0.f,0.f};
    f4 xr1 = {0.f,0.f,0.f,0.f};
    f4 xr2 = {0.f,0.f,0.f,0.f};
    f4 xr3 = {0.f,0.f,0.f,0.f};
    #pragma unroll
    for (int c = 0; c < NCH; ++c) {
        const int base = (c * 512 + i) * 64;
        xr0 += xp4[base + 0 * 16 + m16];
        xr1 += xp4[base + 1 * 16 + m16];
        xr2 += xp4[base + 2 * 16 + m16];
        xr3 += xp4[base + 3 * 16 + m16];
    }

    #pragma unroll
    for (int c2 = 0; c2 < 4; ++c2) {
        const int l = lw + (c2 << 2) + lq;
        f4 s = wv[(c2 << 2) + 0] * xr0
             + wv[(c2 << 2) + 1] * xr1
             + wv[(c2 << 2) + 2] * xr2
             + wv[(c2 << 2) + 3] * xr3;
        float p = s.x + s.y + s.z + s.w;
        p += __shfl_xor(p, 1);
        p += __shfl_xor(p, 2);
        p += __shfl_xor(p, 4);
        p += __shfl_xor(p, 8);
        if (m16 == 0) y[b * 64 + l] = p;
    }
}

extern "C" void kernel_launch(void* const* d_in, const int* in_sizes, int n_in,
                              void* d_out, int out_size, void* d_ws, size_t ws_size,
                              hipStream_t stream) {
    const float* x  = (const float*)d_in[0];   // 131072
    const float* Ci = (const float*)d_in[1];   // 512*4*512*4
    const float* Wi = (const float*)d_in[2];   // 512*4*4*64*64
    float* y  = (float*)d_out;                 // 512*4*64
    float* xr = (float*)d_ws;                  // NCH*512*256 floats = 4 MiB

    route_kernel<<<dim3(128, NCH), 256, 0, stream>>>(x, Ci, xr);
    transform_kernel<<<2048, 256, 0, stream>>>(Wi, xr, y);
}